// Round 4
// baseline (491.853 us; speedup 1.0000x reference)
//
#include <hip/hip_runtime.h>
#include <math.h>

#define B_ 32
#define T_ 256
#define H_ 128
#define KL_ 500
#define KS_ 10

// ---------------- K1: convs (+ fused hb) ----------------
// grid (32, 7): blockIdx.y 0..2 = conv_l out-ch, 3..5 = conv_s out-ch, 6 = hb
__global__ void k_front(const float* __restrict__ in1, const float* __restrict__ in2,
                        const float* __restrict__ wl, const float* __restrict__ bl,
                        const float* __restrict__ ws, const float* __restrict__ bs,
                        const float* __restrict__ h, const float* __restrict__ Whh,
                        const float* __restrict__ bh,
                        float* __restrict__ xf, float* __restrict__ hb,
                        float* __restrict__ dout) {
    int b = blockIdx.x, oc = blockIdx.y;
    int t = threadIdx.x;  // 256 threads
    if (oc == 6) {  // hb = h @ Whh.T + bh ; copy h into d_out[32:]
        __shared__ float hrow[128];
        if (t < 128) hrow[t] = h[b * 128 + t];
        __syncthreads();
        if (t < 128) {
            float acc = bh[t];
            #pragma unroll 4
            for (int k = 0; k < 128; ++k) acc += hrow[k] * Whh[t * 128 + k];
            hb[b * 128 + t] = acc;
            dout[32 + b * 128 + t] = hrow[t];
        }
        return;
    }
    __shared__ float s_in[755 * 3];
    __shared__ float s_w[3 * KL_];
    if (oc < 3) {
        int o = oc;
        for (int i = t; i < 755 * 3; i += 256) s_in[i] = in1[b * 755 * 3 + i];
        for (int i = t; i < 3 * KL_; i += 256) s_w[i] = wl[o * 3 * KL_ + i];
        __syncthreads();
        float acc = bl[o];
        for (int i = 0; i < 3; ++i) {
            const float* wrow = &s_w[i * KL_];
            #pragma unroll 4
            for (int k = 0; k < KL_; ++k)
                acc += s_in[(t + k) * 3 + i] * wrow[k];
        }
        xf[(b * T_ + t) * 6 + o] = acc;
    } else {
        int o = oc - 3;
        for (int i = t; i < 265 * 3; i += 256) s_in[i] = in2[b * 265 * 3 + i];
        for (int i = t; i < 3 * KS_; i += 256) s_w[i] = ws[o * 3 * KS_ + i];
        __syncthreads();
        float acc = bs[o];
        for (int i = 0; i < 3; ++i) {
            #pragma unroll
            for (int k = 0; k < KS_; ++k)
                acc += s_in[(t + k) * 3 + i] * s_w[i * KS_ + k];
        }
        xf[(b * T_ + t) * 6 + 3 + o] = acc;
    }
}

// ---------------- K2: out_t -> trvA[t][b][k], trvT[t][k][b], lblT[t][h][b], outq ----------------
__global__ void k_feat(const float* __restrict__ xf, const float* __restrict__ in3,
                       const float* __restrict__ hb, const float* __restrict__ Wih,
                       const float* __restrict__ tk, const float* __restrict__ tv,
                       const float* __restrict__ tq,
                       float* __restrict__ trvA, float* __restrict__ trvT,
                       float* __restrict__ lblT, float* __restrict__ outq) {
    int t = blockIdx.x;
    int tid = threadIdx.x;
    __shared__ float out_s[B_ * H_];
    __shared__ __align__(16) float tkc[16 * H_];
    __shared__ __align__(16) float tvc[16 * H_];
    __shared__ __align__(16) float tqc[16 * H_];

    for (int o = 0; o < 16; ++o) {
        int idx = o * 256 + tid;
        int b = idx >> 7, hh = idx & 127;
        const float* w = &Wih[hh * 9];
        const float* x6 = &xf[(b * T_ + t) * 6];
        const float* x3 = &in3[(b * T_ + t) * 3];
        float acc = hb[idx];
        acc += x6[0] * w[0] + x6[1] * w[1] + x6[2] * w[2]
             + x6[3] * w[3] + x6[4] * w[4] + x6[5] * w[5]
             + x3[0] * w[6] + x3[1] * w[7] + x3[2] * w[8];
        out_s[idx] = acc;
    }
    __syncthreads();

    float a_tr[16], a_lb[16], a_tq[16];
    #pragma unroll
    for (int o = 0; o < 16; ++o) { a_tr[o] = 0.f; a_lb[o] = 0.f; a_tq[o] = 0.f; }
    const bool last = (t == T_ - 1);

    for (int kc = 0; kc < 8; ++kc) {
        __syncthreads();
        {
            const float4* s1 = (const float4*)(tk + kc * 2048);
            const float4* s2 = (const float4*)(tv + kc * 2048);
            float4* d1 = (float4*)tkc;
            float4* d2 = (float4*)tvc;
            d1[tid * 2]     = s1[tid * 2];
            d1[tid * 2 + 1] = s1[tid * 2 + 1];
            d2[tid * 2]     = s2[tid * 2];
            d2[tid * 2 + 1] = s2[tid * 2 + 1];
            if (last) {
                const float4* s3 = (const float4*)(tq + kc * 2048);
                float4* d3 = (float4*)tqc;
                d3[tid * 2]     = s3[tid * 2];
                d3[tid * 2 + 1] = s3[tid * 2 + 1];
            }
        }
        __syncthreads();
        for (int o = 0; o < 16; ++o) {
            int idx = o * 256 + tid;
            int b = idx >> 7, hh = idx & 127;
            const float* os = &out_s[b * 128 + kc * 16];
            #pragma unroll
            for (int k2 = 0; k2 < 16; ++k2) {
                float ov = os[k2];
                a_tr[o] += ov * tkc[k2 * 128 + hh];
                a_lb[o] += ov * tvc[k2 * 128 + hh];
                if (last) a_tq[o] += ov * tqc[k2 * 128 + hh];
            }
        }
    }
    for (int o = 0; o < 16; ++o) {
        int idx = o * 256 + tid;
        int b = idx >> 7, hh = idx & 127;
        trvA[t * 4096 + idx] = a_tr[o];
        trvT[t * 4096 + hh * 32 + b] = a_tr[o];
        lblT[t * 4096 + hh * 32 + b] = a_lb[o];
        if (last) outq[idx] = a_tq[o];
    }
}

// ---------------- K3: Adam scan — 1 wave per Wm row, register-resident ----------------
// No barriers/fences: single wave, DS ops execute in program order per wave;
// compiler inserts precise lgkmcnt for its own ds_read data deps.
__global__
__attribute__((amdgpu_flat_work_group_size(64, 64), amdgpu_waves_per_eu(1, 1)))
void k_scan(
    const float* __restrict__ trvA, const float* __restrict__ trvT,
    const float* __restrict__ lblT,
    const float* __restrict__ Wm0, const float* __restrict__ bm0,
    const float* __restrict__ outq, float* __restrict__ hi_ws) {
    const int h = blockIdx.x;
    const int lane = threadIdx.x;            // 0..63
    const int row = lane >> 1;
    const int hf = lane & 1;
    const int hf64 = hf * 64;
    const int rowbase = row * 128 + hf64;    // into trvA[t]
    const int colbase = lane * 64;           // into trvT[t] (k=2*lane, 64 consecutive floats)
    const int lblidx = h * 32 + row;

    __shared__ __align__(16) float w_s[H_];

    // Adam state: this lane owns Wm[h][2*lane], Wm[h][2*lane+1]
    float2 wv = *(const float2*)&Wm0[h * 128 + 2 * lane];
    float w0 = wv.x, w1 = wv.y;
    float mW0 = 0.f, vW0 = 0.f, mW1 = 0.f, vW1 = 0.f;
    float bm = bm0[h];
    float mb = 0.f, vb = 0.f, pb1 = 1.f, pb2 = 1.f;

    *(float2*)&w_s[2 * lane] = wv;

    float4 rw[16], cl[16];
    float lbl;
    {
        const float4* rs = (const float4*)(trvA + rowbase);
        #pragma unroll
        for (int j = 0; j < 16; ++j) rw[j] = rs[j];
        const float4* cs = (const float4*)(trvT + colbase);
        #pragma unroll
        for (int j = 0; j < 16; ++j) cl[j] = cs[j];
        lbl = lblT[lblidx];
    }

    const float cg = 2.0f / 4096.0f;
    const float lr = 0.01f, BB1 = 0.9f, BB2 = 0.999f, EPS = 1e-8f;

    for (int t = 0; t < T_; ++t) {
        // ---- phase A: pred partial over this lane's 64-float row half ----
        float ax = 0.f, ay = 0.f, az = 0.f, aw = 0.f;
        #pragma unroll
        for (int j = 0; j < 16; ++j) {
            float4 wv4 = *(const float4*)&w_s[hf64 + 4 * j];
            float4 xv = rw[j];
            ax = fmaf(xv.x, wv4.x, ax); ay = fmaf(xv.y, wv4.y, ay);
            az = fmaf(xv.z, wv4.z, az); aw = fmaf(xv.w, wv4.w, aw);
        }
        float pp = (ax + az) + (ay + aw);
        // pair sum via DPP quad_perm [1,0,3,2] (xor 1) — VALU latency, no LDS
        int po = __builtin_amdgcn_update_dpp(0, __float_as_int(pp), 0xB1, 0xF, 0xF, true);
        float pred = pp + __int_as_float(po);
        float g = cg * (pred + bm - lbl);

        // prefetch rows + lbl for t+1 (rw just consumed; lands during phase B)
        if (t + 1 < T_) {
            const float4* rs = (const float4*)(trvA + (size_t)(t + 1) * 4096 + rowbase);
            #pragma unroll
            for (int j = 0; j < 16; ++j) rw[j] = rs[j];
            lbl = lblT[(size_t)(t + 1) * 4096 + lblidx];
        }

        // ---- g broadcast: 32 readlanes into scalar regs ----
        float ga[32];
        #pragma unroll
        for (int b = 0; b < 32; ++b)
            ga[b] = __int_as_float(__builtin_amdgcn_readlane(__float_as_int(g), 2 * b));

        // ---- phase B: gW for this lane's two columns (all register-local) ----
        float e00 = 0.f, e01 = 0.f, e02 = 0.f, e03 = 0.f;
        float e10 = 0.f, e11 = 0.f, e12 = 0.f, e13 = 0.f;
        #pragma unroll
        for (int q = 0; q < 8; ++q) {
            float4 c0 = cl[q];       // trv[4q..4q+3][2*lane]
            float4 c1 = cl[8 + q];   // trv[4q..4q+3][2*lane+1]
            e00 = fmaf(ga[4 * q + 0], c0.x, e00); e01 = fmaf(ga[4 * q + 1], c0.y, e01);
            e02 = fmaf(ga[4 * q + 2], c0.z, e02); e03 = fmaf(ga[4 * q + 3], c0.w, e03);
            e10 = fmaf(ga[4 * q + 0], c1.x, e10); e11 = fmaf(ga[4 * q + 1], c1.y, e11);
            e12 = fmaf(ga[4 * q + 2], c1.z, e12); e13 = fmaf(ga[4 * q + 3], c1.w, e13);
        }
        const float gk0 = (e00 + e02) + (e01 + e03);
        const float gk1 = (e10 + e12) + (e11 + e13);

        // prefetch cols for t+1 (cl just consumed; lands during next phase A)
        if (t + 1 < T_) {
            const float4* cs = (const float4*)(trvT + (size_t)(t + 1) * 4096 + colbase);
            #pragma unroll
            for (int j = 0; j < 16; ++j) cl[j] = cs[j];
        }

        // ---- Adam (fast rcp/sqrt: ~1ULP, accumulated err << threshold) ----
        pb1 *= BB1; pb2 *= BB2;
        const float rb1 = __builtin_amdgcn_rcpf(1.0f - pb1);
        const float rb2 = __builtin_amdgcn_rcpf(1.0f - pb2);

        mW0 = BB1 * mW0 + (1.0f - BB1) * gk0;
        vW0 = BB2 * vW0 + (1.0f - BB2) * gk0 * gk0;
        w0 = fmaf(-lr * mW0 * rb1,
                  __builtin_amdgcn_rcpf(__builtin_amdgcn_sqrtf(vW0 * rb2) + EPS), w0);
        mW1 = BB1 * mW1 + (1.0f - BB1) * gk1;
        vW1 = BB2 * vW1 + (1.0f - BB2) * gk1 * gk1;
        w1 = fmaf(-lr * mW1 * rb1,
                  __builtin_amdgcn_rcpf(__builtin_amdgcn_sqrtf(vW1 * rb2) + EPS), w1);
        *(float2*)&w_s[2 * lane] = make_float2(w0, w1);

        // bias Adam (redundant on all lanes) — VALU tree over the scalar ga[]
        float s0 = 0.f, s1 = 0.f, s2 = 0.f, s3 = 0.f;
        #pragma unroll
        for (int b = 0; b < 32; b += 4) {
            s0 += ga[b]; s1 += ga[b + 1]; s2 += ga[b + 2]; s3 += ga[b + 3];
        }
        const float gs = (s0 + s2) + (s1 + s3);
        mb = BB1 * mb + (1.0f - BB1) * gs;
        vb = BB2 * vb + (1.0f - BB2) * gs * gs;
        bm = fmaf(-lr * mb * rb1,
                  __builtin_amdgcn_rcpf(__builtin_amdgcn_sqrtf(vb * rb2) + EPS), bm);
    }

    // ---- epilogue: hi[:,h] = outq @ Wm_final[h,:] + bm_final ----
    {
        const float4* es = (const float4*)(outq + rowbase);
        float ax = 0.f, ay = 0.f, az = 0.f, aw = 0.f;
        #pragma unroll
        for (int j = 0; j < 16; ++j) {
            float4 xv = es[j];
            float4 wv4 = *(const float4*)&w_s[hf64 + 4 * j];
            ax = fmaf(xv.x, wv4.x, ax); ay = fmaf(xv.y, wv4.y, ay);
            az = fmaf(xv.z, wv4.z, az); aw = fmaf(xv.w, wv4.w, aw);
        }
        float pp = (ax + az) + (ay + aw);
        int po = __builtin_amdgcn_update_dpp(0, __float_as_int(pp), 0xB1, 0xF, 0xF, true);
        float pred = pp + __int_as_float(po);
        if (hf == 0) hi_ws[row * 128 + h] = pred + bm;
    }
}

// ---------------- K4: y = hi@W_ho.T + b_o ; out = y@out_W.T + out_b ----------------
__global__ void k_out(const float* __restrict__ hi, const float* __restrict__ Who,
                      const float* __restrict__ bo, const float* __restrict__ outW,
                      const float* __restrict__ outb, float* __restrict__ dout) {
    int b = blockIdx.x, hh = threadIdx.x;  // 32 blocks x 128 threads
    __shared__ float hrow[128];
    __shared__ float part[2];
    hrow[hh] = hi[b * 128 + hh];
    __syncthreads();
    float acc = bo[hh];
    #pragma unroll 4
    for (int k = 0; k < 128; ++k) acc += hrow[k] * Who[hh * 128 + k];
    float v = acc * outW[hh];
    v += __shfl_down(v, 32, 64);
    v += __shfl_down(v, 16, 64);
    v += __shfl_down(v, 8, 64);
    v += __shfl_down(v, 4, 64);
    v += __shfl_down(v, 2, 64);
    v += __shfl_down(v, 1, 64);
    if ((hh & 63) == 0) part[hh >> 6] = v;
    __syncthreads();
    if (hh == 0) dout[b] = part[0] + part[1] + outb[0];
}

extern "C" void kernel_launch(void* const* d_in, const int* in_sizes, int n_in,
                              void* d_out, int out_size, void* d_ws, size_t ws_size,
                              hipStream_t stream) {
    (void)in_sizes; (void)n_in; (void)out_size; (void)ws_size;
    const float* in1   = (const float*)d_in[0];   // [32,755,3]
    const float* in2   = (const float*)d_in[1];   // [32,265,3]
    const float* in3   = (const float*)d_in[2];   // [32,256,3]
    const float* h     = (const float*)d_in[3];   // [32,128]
    const float* Wih   = (const float*)d_in[4];   // [128,9]
    const float* Whh   = (const float*)d_in[5];   // [128,128]
    const float* bh    = (const float*)d_in[6];   // [128]
    const float* Who   = (const float*)d_in[7];   // [128,128]
    const float* bo    = (const float*)d_in[8];   // [128]
    const float* wl    = (const float*)d_in[9];   // [3,3,500]
    const float* bl    = (const float*)d_in[10];  // [3]
    const float* wsc   = (const float*)d_in[11];  // [3,3,10]
    const float* bsc   = (const float*)d_in[12];  // [3]
    const float* tk    = (const float*)d_in[13];  // [1,128,128]
    const float* tv    = (const float*)d_in[14];
    const float* tq    = (const float*)d_in[15];
    const float* Wm0   = (const float*)d_in[16];  // [128,128]
    const float* bm0   = (const float*)d_in[17];  // [128]
    const float* outW  = (const float*)d_in[18];  // [1,128]
    const float* outb  = (const float*)d_in[19];  // [1]
    float* out = (float*)d_out;

    float* wsf = (float*)d_ws;
    float* xf    = wsf;                       // 49152
    float* hb    = wsf + 49152;               // 4096
    float* trvA  = wsf + 53248;               // 1048576
    float* trvT  = wsf + 53248 + 1048576;     // 1048576
    float* lblT  = wsf + 53248 + 2097152;     // 1048576
    float* outq  = wsf + 53248 + 3145728;     // 4096
    float* hi_ws = wsf + 53248 + 3149824;     // 4096

    k_front<<<dim3(32, 7), 256, 0, stream>>>(in1, in2, wl, bl, wsc, bsc,
                                             h, Whh, bh, xf, hb, out);
    k_feat<<<256, 256, 0, stream>>>(xf, in3, hb, Wih, tk, tv, tq,
                                    trvA, trvT, lblT, outq);
    k_scan<<<128, 64, 0, stream>>>(trvA, trvT, lblT, Wm0, bm0, outq, hi_ws);
    k_out<<<32, 128, 0, stream>>>(hi_ws, Who, bo, outW, outb, out);
}

// Round 5
// 467.318 us; speedup vs baseline: 1.0525x; 1.0525x over previous
//
#include <hip/hip_runtime.h>
#include <math.h>

#define B_ 32
#define T_ 256
#define H_ 128
#define KL_ 500
#define KS_ 10

// ---------------- K1: convs (+ fused hb) ----------------
// grid (32, 7): blockIdx.y 0..2 = conv_l out-ch, 3..5 = conv_s out-ch, 6 = hb
__global__ void k_front(const float* __restrict__ in1, const float* __restrict__ in2,
                        const float* __restrict__ wl, const float* __restrict__ bl,
                        const float* __restrict__ ws, const float* __restrict__ bs,
                        const float* __restrict__ h, const float* __restrict__ Whh,
                        const float* __restrict__ bh,
                        float* __restrict__ xf, float* __restrict__ hb,
                        float* __restrict__ dout) {
    int b = blockIdx.x, oc = blockIdx.y;
    int t = threadIdx.x;  // 256 threads
    if (oc == 6) {  // hb = h @ Whh.T + bh ; copy h into d_out[32:]
        __shared__ float hrow[128];
        if (t < 128) hrow[t] = h[b * 128 + t];
        __syncthreads();
        if (t < 128) {
            float acc = bh[t];
            #pragma unroll 4
            for (int k = 0; k < 128; ++k) acc += hrow[k] * Whh[t * 128 + k];
            hb[b * 128 + t] = acc;
            dout[32 + b * 128 + t] = hrow[t];
        }
        return;
    }
    __shared__ float s_in[755 * 3];
    __shared__ float s_w[3 * KL_];
    if (oc < 3) {
        int o = oc;
        for (int i = t; i < 755 * 3; i += 256) s_in[i] = in1[b * 755 * 3 + i];
        for (int i = t; i < 3 * KL_; i += 256) s_w[i] = wl[o * 3 * KL_ + i];
        __syncthreads();
        float acc = bl[o];
        for (int i = 0; i < 3; ++i) {
            const float* wrow = &s_w[i * KL_];
            #pragma unroll 4
            for (int k = 0; k < KL_; ++k)
                acc += s_in[(t + k) * 3 + i] * wrow[k];
        }
        xf[(b * T_ + t) * 6 + o] = acc;
    } else {
        int o = oc - 3;
        for (int i = t; i < 265 * 3; i += 256) s_in[i] = in2[b * 265 * 3 + i];
        for (int i = t; i < 3 * KS_; i += 256) s_w[i] = ws[o * 3 * KS_ + i];
        __syncthreads();
        float acc = bs[o];
        for (int i = 0; i < 3; ++i) {
            #pragma unroll
            for (int k = 0; k < KS_; ++k)
                acc += s_in[(t + k) * 3 + i] * s_w[i * KS_ + k];
        }
        xf[(b * T_ + t) * 6 + 3 + o] = acc;
    }
}

// ---------------- K2: out_t -> trvA[t][b][k], trvT[t][k][b], lblT[t][h][b], outq ----------------
__global__ void k_feat(const float* __restrict__ xf, const float* __restrict__ in3,
                       const float* __restrict__ hb, const float* __restrict__ Wih,
                       const float* __restrict__ tk, const float* __restrict__ tv,
                       const float* __restrict__ tq,
                       float* __restrict__ trvA, float* __restrict__ trvT,
                       float* __restrict__ lblT, float* __restrict__ outq) {
    int t = blockIdx.x;
    int tid = threadIdx.x;
    __shared__ float out_s[B_ * H_];
    __shared__ __align__(16) float tkc[16 * H_];
    __shared__ __align__(16) float tvc[16 * H_];
    __shared__ __align__(16) float tqc[16 * H_];

    for (int o = 0; o < 16; ++o) {
        int idx = o * 256 + tid;
        int b = idx >> 7, hh = idx & 127;
        const float* w = &Wih[hh * 9];
        const float* x6 = &xf[(b * T_ + t) * 6];
        const float* x3 = &in3[(b * T_ + t) * 3];
        float acc = hb[idx];
        acc += x6[0] * w[0] + x6[1] * w[1] + x6[2] * w[2]
             + x6[3] * w[3] + x6[4] * w[4] + x6[5] * w[5]
             + x3[0] * w[6] + x3[1] * w[7] + x3[2] * w[8];
        out_s[idx] = acc;
    }
    __syncthreads();

    float a_tr[16], a_lb[16], a_tq[16];
    #pragma unroll
    for (int o = 0; o < 16; ++o) { a_tr[o] = 0.f; a_lb[o] = 0.f; a_tq[o] = 0.f; }
    const bool last = (t == T_ - 1);

    for (int kc = 0; kc < 8; ++kc) {
        __syncthreads();
        {
            const float4* s1 = (const float4*)(tk + kc * 2048);
            const float4* s2 = (const float4*)(tv + kc * 2048);
            float4* d1 = (float4*)tkc;
            float4* d2 = (float4*)tvc;
            d1[tid * 2]     = s1[tid * 2];
            d1[tid * 2 + 1] = s1[tid * 2 + 1];
            d2[tid * 2]     = s2[tid * 2];
            d2[tid * 2 + 1] = s2[tid * 2 + 1];
            if (last) {
                const float4* s3 = (const float4*)(tq + kc * 2048);
                float4* d3 = (float4*)tqc;
                d3[tid * 2]     = s3[tid * 2];
                d3[tid * 2 + 1] = s3[tid * 2 + 1];
            }
        }
        __syncthreads();
        for (int o = 0; o < 16; ++o) {
            int idx = o * 256 + tid;
            int b = idx >> 7, hh = idx & 127;
            const float* os = &out_s[b * 128 + kc * 16];
            #pragma unroll
            for (int k2 = 0; k2 < 16; ++k2) {
                float ov = os[k2];
                a_tr[o] += ov * tkc[k2 * 128 + hh];
                a_lb[o] += ov * tvc[k2 * 128 + hh];
                if (last) a_tq[o] += ov * tqc[k2 * 128 + hh];
            }
        }
    }
    for (int o = 0; o < 16; ++o) {
        int idx = o * 256 + tid;
        int b = idx >> 7, hh = idx & 127;
        trvA[t * 4096 + idx] = a_tr[o];
        trvT[t * 4096 + hh * 32 + b] = a_tr[o];
        lblT[t * 4096 + hh * 32 + b] = a_lb[o];
        if (last) outq[idx] = a_tq[o];
    }
}

// ---------------- K3: Adam scan — 1 wave/row, straight-line, depth-2 prefetch ----------------
// Single-BB loop body (no conditionals, no fences) so SIInsertWaitcnts emits
// precise counted vmcnt waits; loads for t+2 issue in step t -> ~2 iterations of
// latency cover (HBM-safe). Prefetch addrs clamp to 255 via uniform ternary.
#define SCAN_STEP(RW, CL, LB, TT)                                                  \
  do {                                                                             \
    /* phase A: pred partial over this lane's 64-float row half */                 \
    float ax = 0.f, ay = 0.f, az = 0.f, aw = 0.f;                                  \
    _Pragma("unroll")                                                              \
    for (int j = 0; j < 16; ++j) {                                                 \
      float4 wv4 = *(const float4*)&w_s[hf64 + 4 * j];                             \
      float4 xv = RW[j];                                                           \
      ax = fmaf(xv.x, wv4.x, ax); ay = fmaf(xv.y, wv4.y, ay);                      \
      az = fmaf(xv.z, wv4.z, az); aw = fmaf(xv.w, wv4.w, aw);                      \
    }                                                                              \
    float pp = (ax + az) + (ay + aw);                                              \
    int po = __builtin_amdgcn_update_dpp(0, __float_as_int(pp), 0xB1, 0xF, 0xF,    \
                                         true);                                    \
    float pred = pp + __int_as_float(po);                                          \
    float g = cg * (pred + bm - LB);                                               \
    /* prefetch rows + lbl for TT+2 into the just-consumed set */                  \
    {                                                                              \
      const int tpre = ((TT) + 2 < 256) ? ((TT) + 2) : 255;                        \
      const float4* rs = (const float4*)(trvA + (size_t)tpre * 4096 + rowbase);    \
      _Pragma("unroll")                                                            \
      for (int j = 0; j < 16; ++j) RW[j] = rs[j];                                  \
      LB = lblT[(size_t)tpre * 4096 + lblidx];                                     \
    }                                                                              \
    /* g broadcast: 32 readlanes into scalar regs */                               \
    float ga[32];                                                                  \
    _Pragma("unroll")                                                              \
    for (int b = 0; b < 32; ++b)                                                   \
      ga[b] = __int_as_float(                                                      \
          __builtin_amdgcn_readlane(__float_as_int(g), 2 * b));                    \
    /* phase B: gW for this lane's two columns (register-local) */                 \
    float e00 = 0.f, e01 = 0.f, e02 = 0.f, e03 = 0.f;                              \
    float e10 = 0.f, e11 = 0.f, e12 = 0.f, e13 = 0.f;                              \
    _Pragma("unroll")                                                              \
    for (int q = 0; q < 8; ++q) {                                                  \
      float4 c0 = CL[q];                                                           \
      float4 c1 = CL[8 + q];                                                       \
      e00 = fmaf(ga[4 * q + 0], c0.x, e00); e01 = fmaf(ga[4 * q + 1], c0.y, e01);  \
      e02 = fmaf(ga[4 * q + 2], c0.z, e02); e03 = fmaf(ga[4 * q + 3], c0.w, e03);  \
      e10 = fmaf(ga[4 * q + 0], c1.x, e10); e11 = fmaf(ga[4 * q + 1], c1.y, e11);  \
      e12 = fmaf(ga[4 * q + 2], c1.z, e12); e13 = fmaf(ga[4 * q + 3], c1.w, e13);  \
    }                                                                              \
    const float gk0 = (e00 + e02) + (e01 + e03);                                   \
    const float gk1 = (e10 + e12) + (e11 + e13);                                   \
    /* prefetch cols for TT+2 into the just-consumed set */                        \
    {                                                                              \
      const int tpre = ((TT) + 2 < 256) ? ((TT) + 2) : 255;                        \
      const float4* cs = (const float4*)(trvT + (size_t)tpre * 4096 + colbase);    \
      _Pragma("unroll")                                                            \
      for (int j = 0; j < 16; ++j) CL[j] = cs[j];                                  \
    }                                                                              \
    /* Adam (fast rcp/sqrt) */                                                     \
    pb1 *= BB1; pb2 *= BB2;                                                        \
    const float rb1 = __builtin_amdgcn_rcpf(1.0f - pb1);                           \
    const float rb2 = __builtin_amdgcn_rcpf(1.0f - pb2);                           \
    mW0 = BB1 * mW0 + (1.0f - BB1) * gk0;                                          \
    vW0 = BB2 * vW0 + (1.0f - BB2) * gk0 * gk0;                                    \
    w0 = fmaf(-lr * mW0 * rb1,                                                     \
              __builtin_amdgcn_rcpf(__builtin_amdgcn_sqrtf(vW0 * rb2) + EPS), w0); \
    mW1 = BB1 * mW1 + (1.0f - BB1) * gk1;                                          \
    vW1 = BB2 * vW1 + (1.0f - BB2) * gk1 * gk1;                                    \
    w1 = fmaf(-lr * mW1 * rb1,                                                     \
              __builtin_amdgcn_rcpf(__builtin_amdgcn_sqrtf(vW1 * rb2) + EPS), w1); \
    *(float2*)&w_s[2 * lane] = make_float2(w0, w1);                                \
    /* bias Adam (redundant on all lanes) over the scalar ga[] */                  \
    float s0 = 0.f, s1 = 0.f, s2 = 0.f, s3 = 0.f;                                  \
    _Pragma("unroll")                                                              \
    for (int b = 0; b < 32; b += 4) {                                              \
      s0 += ga[b]; s1 += ga[b + 1]; s2 += ga[b + 2]; s3 += ga[b + 3];              \
    }                                                                              \
    const float gs = (s0 + s2) + (s1 + s3);                                        \
    mb = BB1 * mb + (1.0f - BB1) * gs;                                             \
    vb = BB2 * vb + (1.0f - BB2) * gs * gs;                                        \
    bm = fmaf(-lr * mb * rb1,                                                      \
              __builtin_amdgcn_rcpf(__builtin_amdgcn_sqrtf(vb * rb2) + EPS), bm);  \
  } while (0)

__global__
__attribute__((amdgpu_flat_work_group_size(64, 64), amdgpu_waves_per_eu(1, 1)))
void k_scan(
    const float* __restrict__ trvA, const float* __restrict__ trvT,
    const float* __restrict__ lblT,
    const float* __restrict__ Wm0, const float* __restrict__ bm0,
    const float* __restrict__ outq, float* __restrict__ hi_ws) {
    const int h = blockIdx.x;
    const int lane = threadIdx.x;            // 0..63
    const int row = lane >> 1;
    const int hf = lane & 1;
    const int hf64 = hf * 64;
    const int rowbase = row * 128 + hf64;    // into trvA[t]
    const int colbase = lane * 64;           // into trvT[t]
    const int lblidx = h * 32 + row;

    __shared__ __align__(16) float w_s[H_];

    // Adam state: this lane owns Wm[h][2*lane], Wm[h][2*lane+1]
    float2 wv = *(const float2*)&Wm0[h * 128 + 2 * lane];
    float w0 = wv.x, w1 = wv.y;
    float mW0 = 0.f, vW0 = 0.f, mW1 = 0.f, vW1 = 0.f;
    float bm = bm0[h];
    float mb = 0.f, vb = 0.f, pb1 = 1.f, pb2 = 1.f;

    *(float2*)&w_s[2 * lane] = wv;

    // depth-2 pipeline: set A = even t, set B = odd t
    float4 rwA[16], rwB[16], clA[16], clB[16];
    float lA, lB;
    {
        const float4* r0 = (const float4*)(trvA + rowbase);
        const float4* c0 = (const float4*)(trvT + colbase);
        const float4* r1 = (const float4*)(trvA + 4096 + rowbase);
        const float4* c1 = (const float4*)(trvT + 4096 + colbase);
        #pragma unroll
        for (int j = 0; j < 16; ++j) rwA[j] = r0[j];
        #pragma unroll
        for (int j = 0; j < 16; ++j) clA[j] = c0[j];
        lA = lblT[lblidx];
        #pragma unroll
        for (int j = 0; j < 16; ++j) rwB[j] = r1[j];
        #pragma unroll
        for (int j = 0; j < 16; ++j) clB[j] = c1[j];
        lB = lblT[4096 + lblidx];
    }

    const float cg = 2.0f / 4096.0f;
    const float lr = 0.01f, BB1 = 0.9f, BB2 = 0.999f, EPS = 1e-8f;

    for (int t = 0; t < T_; t += 2) {
        SCAN_STEP(rwA, clA, lA, t);
        SCAN_STEP(rwB, clB, lB, t + 1);
    }

    // ---- epilogue: hi[:,h] = outq @ Wm_final[h,:] + bm_final ----
    {
        const float4* es = (const float4*)(outq + rowbase);
        float ax = 0.f, ay = 0.f, az = 0.f, aw = 0.f;
        #pragma unroll
        for (int j = 0; j < 16; ++j) {
            float4 xv = es[j];
            float4 wv4 = *(const float4*)&w_s[hf64 + 4 * j];
            ax = fmaf(xv.x, wv4.x, ax); ay = fmaf(xv.y, wv4.y, ay);
            az = fmaf(xv.z, wv4.z, az); aw = fmaf(xv.w, wv4.w, aw);
        }
        float pp = (ax + az) + (ay + aw);
        int po = __builtin_amdgcn_update_dpp(0, __float_as_int(pp), 0xB1, 0xF, 0xF, true);
        float pred = pp + __int_as_float(po);
        if (hf == 0) hi_ws[row * 128 + h] = pred + bm;
    }
}

// ---------------- K4: y = hi@W_ho.T + b_o ; out = y@out_W.T + out_b ----------------
__global__ void k_out(const float* __restrict__ hi, const float* __restrict__ Who,
                      const float* __restrict__ bo, const float* __restrict__ outW,
                      const float* __restrict__ outb, float* __restrict__ dout) {
    int b = blockIdx.x, hh = threadIdx.x;  // 32 blocks x 128 threads
    __shared__ float hrow[128];
    __shared__ float part[2];
    hrow[hh] = hi[b * 128 + hh];
    __syncthreads();
    float acc = bo[hh];
    #pragma unroll 4
    for (int k = 0; k < 128; ++k) acc += hrow[k] * Who[hh * 128 + k];
    float v = acc * outW[hh];
    v += __shfl_down(v, 32, 64);
    v += __shfl_down(v, 16, 64);
    v += __shfl_down(v, 8, 64);
    v += __shfl_down(v, 4, 64);
    v += __shfl_down(v, 2, 64);
    v += __shfl_down(v, 1, 64);
    if ((hh & 63) == 0) part[hh >> 6] = v;
    __syncthreads();
    if (hh == 0) dout[b] = part[0] + part[1] + outb[0];
}

extern "C" void kernel_launch(void* const* d_in, const int* in_sizes, int n_in,
                              void* d_out, int out_size, void* d_ws, size_t ws_size,
                              hipStream_t stream) {
    (void)in_sizes; (void)n_in; (void)out_size; (void)ws_size;
    const float* in1   = (const float*)d_in[0];   // [32,755,3]
    const float* in2   = (const float*)d_in[1];   // [32,265,3]
    const float* in3   = (const float*)d_in[2];   // [32,256,3]
    const float* h     = (const float*)d_in[3];   // [32,128]
    const float* Wih   = (const float*)d_in[4];   // [128,9]
    const float* Whh   = (const float*)d_in[5];   // [128,128]
    const float* bh    = (const float*)d_in[6];   // [128]
    const float* Who   = (const float*)d_in[7];   // [128,128]
    const float* bo    = (const float*)d_in[8];   // [128]
    const float* wl    = (const float*)d_in[9];   // [3,3,500]
    const float* bl    = (const float*)d_in[10];  // [3]
    const float* wsc   = (const float*)d_in[11];  // [3,3,10]
    const float* bsc   = (const float*)d_in[12];  // [3]
    const float* tk    = (const float*)d_in[13];  // [1,128,128]
    const float* tv    = (const float*)d_in[14];
    const float* tq    = (const float*)d_in[15];
    const float* Wm0   = (const float*)d_in[16];  // [128,128]
    const float* bm0   = (const float*)d_in[17];  // [128]
    const float* outW  = (const float*)d_in[18];  // [1,128]
    const float* outb  = (const float*)d_in[19];  // [1]
    float* out = (float*)d_out;

    float* wsf = (float*)d_ws;
    float* xf    = wsf;                       // 49152
    float* hb    = wsf + 49152;               // 4096
    float* trvA  = wsf + 53248;               // 1048576
    float* trvT  = wsf + 53248 + 1048576;     // 1048576
    float* lblT  = wsf + 53248 + 2097152;     // 1048576
    float* outq  = wsf + 53248 + 3145728;     // 4096
    float* hi_ws = wsf + 53248 + 3149824;     // 4096

    k_front<<<dim3(32, 7), 256, 0, stream>>>(in1, in2, wl, bl, wsc, bsc,
                                             h, Whh, bh, xf, hb, out);
    k_feat<<<256, 256, 0, stream>>>(xf, in3, hb, Wih, tk, tv, tq,
                                    trvA, trvT, lblT, outq);
    k_scan<<<128, 64, 0, stream>>>(trvA, trvT, lblT, Wm0, bm0, outq, hi_ws);
    k_out<<<32, 128, 0, stream>>>(hi_ws, Who, bo, outW, outb, out);
}

// Round 6
// 374.319 us; speedup vs baseline: 1.3140x; 1.2484x over previous
//
#include <hip/hip_runtime.h>
#include <math.h>

#define B_ 32
#define T_ 256
#define H_ 128
#define KL_ 500
#define KS_ 10

// ---------------- K1: convs (+ fused hb) ----------------
// grid (32, 7): blockIdx.y 0..2 = conv_l out-ch, 3..5 = conv_s out-ch, 6 = hb
__global__ void k_front(const float* __restrict__ in1, const float* __restrict__ in2,
                        const float* __restrict__ wl, const float* __restrict__ bl,
                        const float* __restrict__ ws, const float* __restrict__ bs,
                        const float* __restrict__ h, const float* __restrict__ Whh,
                        const float* __restrict__ bh,
                        float* __restrict__ xf, float* __restrict__ hb,
                        float* __restrict__ dout) {
    int b = blockIdx.x, oc = blockIdx.y;
    int t = threadIdx.x;  // 256 threads
    if (oc == 6) {  // hb = h @ Whh.T + bh ; copy h into d_out[32:]
        __shared__ float hrow[128];
        if (t < 128) hrow[t] = h[b * 128 + t];
        __syncthreads();
        if (t < 128) {
            float acc = bh[t];
            #pragma unroll 4
            for (int k = 0; k < 128; ++k) acc += hrow[k] * Whh[t * 128 + k];
            hb[b * 128 + t] = acc;
            dout[32 + b * 128 + t] = hrow[t];
        }
        return;
    }
    __shared__ float s_in[755 * 3];
    __shared__ float s_w[3 * KL_];
    if (oc < 3) {
        int o = oc;
        for (int i = t; i < 755 * 3; i += 256) s_in[i] = in1[b * 755 * 3 + i];
        for (int i = t; i < 3 * KL_; i += 256) s_w[i] = wl[o * 3 * KL_ + i];
        __syncthreads();
        float acc = bl[o];
        for (int i = 0; i < 3; ++i) {
            const float* wrow = &s_w[i * KL_];
            #pragma unroll 4
            for (int k = 0; k < KL_; ++k)
                acc += s_in[(t + k) * 3 + i] * wrow[k];
        }
        xf[(b * T_ + t) * 6 + o] = acc;
    } else {
        int o = oc - 3;
        for (int i = t; i < 265 * 3; i += 256) s_in[i] = in2[b * 265 * 3 + i];
        for (int i = t; i < 3 * KS_; i += 256) s_w[i] = ws[o * 3 * KS_ + i];
        __syncthreads();
        float acc = bs[o];
        for (int i = 0; i < 3; ++i) {
            #pragma unroll
            for (int k = 0; k < KS_; ++k)
                acc += s_in[(t + k) * 3 + i] * s_w[i * KS_ + k];
        }
        xf[(b * T_ + t) * 6 + 3 + o] = acc;
    }
}

// ---------------- K2: features -> lane-permuted tiles ----------------
// rwP[t][j][lane] (float4): lane l=2b+hf, j=(k&63)>>2, c=k&3  (phase-A rows)
// clP[t][j][lane] (float4): lane l=k>>1, j=(b>>2)+8*(k&1), c=b&3 (phase-B cols)
// so that k_scan load j reads base + j*1024B + lane*16B — perfectly coalesced.
__global__ void k_feat(const float* __restrict__ xf, const float* __restrict__ in3,
                       const float* __restrict__ hb, const float* __restrict__ Wih,
                       const float* __restrict__ tk, const float* __restrict__ tv,
                       const float* __restrict__ tq,
                       float* __restrict__ rwP, float* __restrict__ clP,
                       float* __restrict__ lblT, float* __restrict__ outq) {
    int t = blockIdx.x;
    int tid = threadIdx.x;
    __shared__ float out_s[B_ * H_];
    __shared__ __align__(16) float tkc[16 * H_];
    __shared__ __align__(16) float tvc[16 * H_];
    __shared__ __align__(16) float tqc[16 * H_];

    for (int o = 0; o < 16; ++o) {
        int idx = o * 256 + tid;
        int b = idx >> 7, hh = idx & 127;
        const float* w = &Wih[hh * 9];
        const float* x6 = &xf[(b * T_ + t) * 6];
        const float* x3 = &in3[(b * T_ + t) * 3];
        float acc = hb[idx];
        acc += x6[0] * w[0] + x6[1] * w[1] + x6[2] * w[2]
             + x6[3] * w[3] + x6[4] * w[4] + x6[5] * w[5]
             + x3[0] * w[6] + x3[1] * w[7] + x3[2] * w[8];
        out_s[idx] = acc;
    }
    __syncthreads();

    float a_tr[16], a_lb[16], a_tq[16];
    #pragma unroll
    for (int o = 0; o < 16; ++o) { a_tr[o] = 0.f; a_lb[o] = 0.f; a_tq[o] = 0.f; }
    const bool last = (t == T_ - 1);

    for (int kc = 0; kc < 8; ++kc) {
        __syncthreads();
        {
            const float4* s1 = (const float4*)(tk + kc * 2048);
            const float4* s2 = (const float4*)(tv + kc * 2048);
            float4* d1 = (float4*)tkc;
            float4* d2 = (float4*)tvc;
            d1[tid * 2]     = s1[tid * 2];
            d1[tid * 2 + 1] = s1[tid * 2 + 1];
            d2[tid * 2]     = s2[tid * 2];
            d2[tid * 2 + 1] = s2[tid * 2 + 1];
            if (last) {
                const float4* s3 = (const float4*)(tq + kc * 2048);
                float4* d3 = (float4*)tqc;
                d3[tid * 2]     = s3[tid * 2];
                d3[tid * 2 + 1] = s3[tid * 2 + 1];
            }
        }
        __syncthreads();
        for (int o = 0; o < 16; ++o) {
            int idx = o * 256 + tid;
            int b = idx >> 7, hh = idx & 127;
            const float* os = &out_s[b * 128 + kc * 16];
            #pragma unroll
            for (int k2 = 0; k2 < 16; ++k2) {
                float ov = os[k2];
                a_tr[o] += ov * tkc[k2 * 128 + hh];
                a_lb[o] += ov * tvc[k2 * 128 + hh];
                if (last) a_tq[o] += ov * tqc[k2 * 128 + hh];
            }
        }
    }
    for (int o = 0; o < 16; ++o) {
        int idx = o * 256 + tid;
        int b = idx >> 7, hh = idx & 127;  // value = trv[t][b][hh]
        // rwP: lane = 2b + (hh>>6), j = (hh&63)>>2, c = hh&3
        rwP[t * 4096 + (((hh & 63) >> 2) << 8) + ((2 * b + (hh >> 6)) << 2) + (hh & 3)] = a_tr[o];
        // clP: lane = hh>>1, j = (b>>2) + 8*(hh&1), c = b&3
        clP[t * 4096 + (((b >> 2) + 8 * (hh & 1)) << 8) + ((hh >> 1) << 2) + (b & 3)] = a_tr[o];
        lblT[t * 4096 + hh * 32 + b] = a_lb[o];
        if (last) outq[idx] = a_tq[o];
    }
}

// ---------------- K3: Adam scan — 1 wave/row, depth-2 prefetch, coalesced loads ----------------
#define SCAN_STEP(RW, CL, LB, TT)                                                  \
  do {                                                                             \
    /* phase A: pred partial over this lane's 64-float row half */                 \
    float ax = 0.f, ay = 0.f, az = 0.f, aw = 0.f;                                  \
    _Pragma("unroll")                                                              \
    for (int j = 0; j < 16; ++j) {                                                 \
      float4 wv4 = *(const float4*)&w_s[hf64 + 4 * j];                             \
      float4 xv = RW[j];                                                           \
      ax = fmaf(xv.x, wv4.x, ax); ay = fmaf(xv.y, wv4.y, ay);                      \
      az = fmaf(xv.z, wv4.z, az); aw = fmaf(xv.w, wv4.w, aw);                      \
    }                                                                              \
    float pp = (ax + az) + (ay + aw);                                              \
    int po = __builtin_amdgcn_update_dpp(0, __float_as_int(pp), 0xB1, 0xF, 0xF,    \
                                         true);                                    \
    float pred = pp + __int_as_float(po);                                          \
    float g = cg * (pred + bm - LB);                                               \
    /* prefetch rows + lbl for TT+2 (coalesced: j*1024B + lane*16B) */             \
    {                                                                              \
      const int tpre = ((TT) + 2 < 256) ? ((TT) + 2) : 255;                        \
      const float4* rs = (const float4*)(rwP + (size_t)tpre * 4096);               \
      _Pragma("unroll")                                                            \
      for (int j = 0; j < 16; ++j) RW[j] = rs[j * 64 + lane];                      \
      LB = lblT[(size_t)tpre * 4096 + lblidx];                                     \
    }                                                                              \
    /* g broadcast: 32 readlanes into scalar regs */                               \
    float ga[32];                                                                  \
    _Pragma("unroll")                                                              \
    for (int b = 0; b < 32; ++b)                                                   \
      ga[b] = __int_as_float(                                                      \
          __builtin_amdgcn_readlane(__float_as_int(g), 2 * b));                    \
    /* phase B: gW for this lane's two columns (register-local) */                 \
    float e00 = 0.f, e01 = 0.f, e02 = 0.f, e03 = 0.f;                              \
    float e10 = 0.f, e11 = 0.f, e12 = 0.f, e13 = 0.f;                              \
    _Pragma("unroll")                                                              \
    for (int q = 0; q < 8; ++q) {                                                  \
      float4 c0 = CL[q];                                                           \
      float4 c1 = CL[8 + q];                                                       \
      e00 = fmaf(ga[4 * q + 0], c0.x, e00); e01 = fmaf(ga[4 * q + 1], c0.y, e01);  \
      e02 = fmaf(ga[4 * q + 2], c0.z, e02); e03 = fmaf(ga[4 * q + 3], c0.w, e03);  \
      e10 = fmaf(ga[4 * q + 0], c1.x, e10); e11 = fmaf(ga[4 * q + 1], c1.y, e11);  \
      e12 = fmaf(ga[4 * q + 2], c1.z, e12); e13 = fmaf(ga[4 * q + 3], c1.w, e13);  \
    }                                                                              \
    const float gk0 = (e00 + e02) + (e01 + e03);                                   \
    const float gk1 = (e10 + e12) + (e11 + e13);                                   \
    /* prefetch cols for TT+2 (coalesced) */                                       \
    {                                                                              \
      const int tpre = ((TT) + 2 < 256) ? ((TT) + 2) : 255;                        \
      const float4* cs = (const float4*)(clP + (size_t)tpre * 4096);               \
      _Pragma("unroll")                                                            \
      for (int j = 0; j < 16; ++j) CL[j] = cs[j * 64 + lane];                      \
    }                                                                              \
    /* Adam (fast rcp/sqrt) */                                                     \
    pb1 *= BB1; pb2 *= BB2;                                                        \
    const float rb1 = __builtin_amdgcn_rcpf(1.0f - pb1);                           \
    const float rb2 = __builtin_amdgcn_rcpf(1.0f - pb2);                           \
    mW0 = BB1 * mW0 + (1.0f - BB1) * gk0;                                          \
    vW0 = BB2 * vW0 + (1.0f - BB2) * gk0 * gk0;                                    \
    w0 = fmaf(-lr * mW0 * rb1,                                                     \
              __builtin_amdgcn_rcpf(__builtin_amdgcn_sqrtf(vW0 * rb2) + EPS), w0); \
    mW1 = BB1 * mW1 + (1.0f - BB1) * gk1;                                          \
    vW1 = BB2 * vW1 + (1.0f - BB2) * gk1 * gk1;                                    \
    w1 = fmaf(-lr * mW1 * rb1,                                                     \
              __builtin_amdgcn_rcpf(__builtin_amdgcn_sqrtf(vW1 * rb2) + EPS), w1); \
    *(float2*)&w_s[2 * lane] = make_float2(w0, w1);                                \
    /* bias Adam (redundant on all lanes) over the scalar ga[] */                  \
    float s0 = 0.f, s1 = 0.f, s2 = 0.f, s3 = 0.f;                                  \
    _Pragma("unroll")                                                              \
    for (int b = 0; b < 32; b += 4) {                                              \
      s0 += ga[b]; s1 += ga[b + 1]; s2 += ga[b + 2]; s3 += ga[b + 3];              \
    }                                                                              \
    const float gs = (s0 + s2) + (s1 + s3);                                        \
    mb = BB1 * mb + (1.0f - BB1) * gs;                                             \
    vb = BB2 * vb + (1.0f - BB2) * gs * gs;                                        \
    bm = fmaf(-lr * mb * rb1,                                                      \
              __builtin_amdgcn_rcpf(__builtin_amdgcn_sqrtf(vb * rb2) + EPS), bm);  \
  } while (0)

__global__
__attribute__((amdgpu_flat_work_group_size(64, 64), amdgpu_waves_per_eu(1, 1)))
void k_scan(
    const float* __restrict__ rwP, const float* __restrict__ clP,
    const float* __restrict__ lblT,
    const float* __restrict__ Wm0, const float* __restrict__ bm0,
    const float* __restrict__ outq, float* __restrict__ hi_ws) {
    const int h = blockIdx.x;
    const int lane = threadIdx.x;            // 0..63
    const int row = lane >> 1;
    const int hf = lane & 1;
    const int hf64 = hf * 64;
    const int rowbase = row * 128 + hf64;    // for outq epilogue only
    const int lblidx = h * 32 + row;

    __shared__ __align__(16) float w_s[H_];

    // Adam state: this lane owns Wm[h][2*lane], Wm[h][2*lane+1]
    float2 wv = *(const float2*)&Wm0[h * 128 + 2 * lane];
    float w0 = wv.x, w1 = wv.y;
    float mW0 = 0.f, vW0 = 0.f, mW1 = 0.f, vW1 = 0.f;
    float bm = bm0[h];
    float mb = 0.f, vb = 0.f, pb1 = 1.f, pb2 = 1.f;

    *(float2*)&w_s[2 * lane] = wv;

    // depth-2 pipeline: set A = even t, set B = odd t
    float4 rwA[16], rwB[16], clA[16], clB[16];
    float lA, lB;
    {
        const float4* r0 = (const float4*)(rwP);
        const float4* c0 = (const float4*)(clP);
        const float4* r1 = (const float4*)(rwP + 4096);
        const float4* c1 = (const float4*)(clP + 4096);
        #pragma unroll
        for (int j = 0; j < 16; ++j) rwA[j] = r0[j * 64 + lane];
        #pragma unroll
        for (int j = 0; j < 16; ++j) clA[j] = c0[j * 64 + lane];
        lA = lblT[lblidx];
        #pragma unroll
        for (int j = 0; j < 16; ++j) rwB[j] = r1[j * 64 + lane];
        #pragma unroll
        for (int j = 0; j < 16; ++j) clB[j] = c1[j * 64 + lane];
        lB = lblT[4096 + lblidx];
    }

    const float cg = 2.0f / 4096.0f;
    const float lr = 0.01f, BB1 = 0.9f, BB2 = 0.999f, EPS = 1e-8f;

    for (int t = 0; t < T_; t += 2) {
        SCAN_STEP(rwA, clA, lA, t);
        SCAN_STEP(rwB, clB, lB, t + 1);
    }

    // ---- epilogue: hi[:,h] = outq @ Wm_final[h,:] + bm_final ----
    {
        const float4* es = (const float4*)(outq + rowbase);
        float ax = 0.f, ay = 0.f, az = 0.f, aw = 0.f;
        #pragma unroll
        for (int j = 0; j < 16; ++j) {
            float4 xv = es[j];
            float4 wv4 = *(const float4*)&w_s[hf64 + 4 * j];
            ax = fmaf(xv.x, wv4.x, ax); ay = fmaf(xv.y, wv4.y, ay);
            az = fmaf(xv.z, wv4.z, az); aw = fmaf(xv.w, wv4.w, aw);
        }
        float pp = (ax + az) + (ay + aw);
        int po = __builtin_amdgcn_update_dpp(0, __float_as_int(pp), 0xB1, 0xF, 0xF, true);
        float pred = pp + __int_as_float(po);
        if (hf == 0) hi_ws[row * 128 + h] = pred + bm;
    }
}

// ---------------- K4: y = hi@W_ho.T + b_o ; out = y@out_W.T + out_b ----------------
__global__ void k_out(const float* __restrict__ hi, const float* __restrict__ Who,
                      const float* __restrict__ bo, const float* __restrict__ outW,
                      const float* __restrict__ outb, float* __restrict__ dout) {
    int b = blockIdx.x, hh = threadIdx.x;  // 32 blocks x 128 threads
    __shared__ float hrow[128];
    __shared__ float part[2];
    hrow[hh] = hi[b * 128 + hh];
    __syncthreads();
    float acc = bo[hh];
    #pragma unroll 4
    for (int k = 0; k < 128; ++k) acc += hrow[k] * Who[hh * 128 + k];
    float v = acc * outW[hh];
    v += __shfl_down(v, 32, 64);
    v += __shfl_down(v, 16, 64);
    v += __shfl_down(v, 8, 64);
    v += __shfl_down(v, 4, 64);
    v += __shfl_down(v, 2, 64);
    v += __shfl_down(v, 1, 64);
    if ((hh & 63) == 0) part[hh >> 6] = v;
    __syncthreads();
    if (hh == 0) dout[b] = part[0] + part[1] + outb[0];
}

extern "C" void kernel_launch(void* const* d_in, const int* in_sizes, int n_in,
                              void* d_out, int out_size, void* d_ws, size_t ws_size,
                              hipStream_t stream) {
    (void)in_sizes; (void)n_in; (void)out_size; (void)ws_size;
    const float* in1   = (const float*)d_in[0];   // [32,755,3]
    const float* in2   = (const float*)d_in[1];   // [32,265,3]
    const float* in3   = (const float*)d_in[2];   // [32,256,3]
    const float* h     = (const float*)d_in[3];   // [32,128]
    const float* Wih   = (const float*)d_in[4];   // [128,9]
    const float* Whh   = (const float*)d_in[5];   // [128,128]
    const float* bh    = (const float*)d_in[6];   // [128]
    const float* Who   = (const float*)d_in[7];   // [128,128]
    const float* bo    = (const float*)d_in[8];   // [128]
    const float* wl    = (const float*)d_in[9];   // [3,3,500]
    const float* bl    = (const float*)d_in[10];  // [3]
    const float* wsc   = (const float*)d_in[11];  // [3,3,10]
    const float* bsc   = (const float*)d_in[12];  // [3]
    const float* tk    = (const float*)d_in[13];  // [1,128,128]
    const float* tv    = (const float*)d_in[14];
    const float* tq    = (const float*)d_in[15];
    const float* Wm0   = (const float*)d_in[16];  // [128,128]
    const float* bm0   = (const float*)d_in[17];  // [128]
    const float* outW  = (const float*)d_in[18];  // [1,128]
    const float* outb  = (const float*)d_in[19];  // [1]
    float* out = (float*)d_out;

    float* wsf = (float*)d_ws;
    float* xf    = wsf;                       // 49152
    float* hb    = wsf + 49152;               // 4096
    float* rwP   = wsf + 53248;               // 1048576
    float* clP   = wsf + 53248 + 1048576;     // 1048576
    float* lblT  = wsf + 53248 + 2097152;     // 1048576
    float* outq  = wsf + 53248 + 3145728;     // 4096
    float* hi_ws = wsf + 53248 + 3149824;     // 4096

    k_front<<<dim3(32, 7), 256, 0, stream>>>(in1, in2, wl, bl, wsc, bsc,
                                             h, Whh, bh, xf, hb, out);
    k_feat<<<256, 256, 0, stream>>>(xf, in3, hb, Wih, tk, tv, tq,
                                    rwP, clP, lblT, outq);
    k_scan<<<128, 64, 0, stream>>>(rwP, clP, lblT, Wm0, bm0, outq, hi_ws);
    k_out<<<32, 128, 0, stream>>>(hi_ws, Who, bo, outW, outb, out);
}